// Round 5
// baseline (153.382 us; speedup 1.0000x reference)
//
#include <hip/hip_runtime.h>

#define NN 2048
#define DD 128
#define KK 64

typedef __attribute__((ext_vector_type(8))) short bf16x8;
typedef __attribute__((ext_vector_type(4))) float f32x4;
#define MFMA_BF16 __builtin_amdgcn_mfma_f32_16x16x32_bf16

// ws layout (ushort units):
//   Gp_bf : [8][32][128][128]   @ 0        (4194304)  bf16 Gram partials (natural, 256-row chunks)
//   Pbf   : [8][128][128]       @ 4194304  (131072)   P = Wq^T Wk, PRE-SWIZZLED (frag image)
//   Wv_bf : [8][128][128]       @ 4325376  (131072)   Wv bf16, PRE-SWIZZLED ([e][d] frag image)
//   x_bf  : [32][16][128][128]  @ 4456448  (8388608)  x hi-bf16, PRE-SWIZZLED ([n][d] frag image)

__device__ __forceinline__ float bf2f(unsigned short h){ return __uint_as_float(((unsigned)h) << 16); }
__device__ __forceinline__ unsigned short f2bf(float f){
  unsigned u = __float_as_uint(f);
  u += 0x7fffu + ((u >> 16) & 1u);   // RTNE
  return (unsigned short)(u >> 16);
}
__device__ __forceinline__ unsigned pack2(float a, float b){
  return (unsigned)f2bf(a) | ((unsigned)f2bf(b) << 16);
}

// swizzled frag load: phys_ushort(r,c) = r*128 + ((c>>3)^(r&7))*8 + (c&7)
__device__ __forceinline__ bf16x8 ldfrag_sw(const unsigned short* base, int row16, int kc, int lane){
  int d = row16 + (lane & 15);
  int q = lane >> 4;
  int ch = ((kc << 2) + q) ^ (d & 7);
  return *(const bf16x8*)(base + d*128 + ch*8);
}

// ---------------- K1: kg (blocks 0..255, 256-row chunks) + kp (256..287: P + Wv cvt) ----------------
__global__ __launch_bounds__(512, 4) void kgkp(const float* __restrict__ x,
                                               const float* __restrict__ Wq,
                                               const float* __restrict__ Wk,
                                               const float* __restrict__ Wv,
                                               unsigned short* __restrict__ Gp_bf,
                                               unsigned short* __restrict__ Pbf,
                                               unsigned short* __restrict__ Wv_bf,
                                               unsigned short* __restrict__ x_bf){
  __shared__ __align__(16) unsigned short sm[32768];   // 64 KB
  const int t = threadIdx.x;
  const int bid = blockIdx.x;
  const int w = t >> 6, lane = t & 63, quad = lane >> 4;
  if (bid < 256){
    unsigned short* xh = sm;            // hi bf16, swizzled [d][n]
    unsigned short* xl = sm + 16384;    // lo
    const int b = bid & 31, chunk = bid >> 5;          // chunk in [0,8), 256 rows
    const int wr = (w >> 1)*32, wc = (w & 1)*64;
    f32x4 acc[2][4] = {};
    for (int sub = 0; sub < 2; ++sub){
      if (sub) __syncthreads();
      const float* xb = x + ((size_t)b*NN + (size_t)(chunk*256 + sub*128))*DD;
      unsigned short* xbo = x_bf + (((size_t)(b*16 + chunk*2 + sub)) << 14);
      for (int it = 0; it < 2; ++it){
        int gidx = it*512 + t;
        int n4g = (gidx & 7) | (((gidx >> 6) & 3) << 3);
        int dcq = ((gidx >> 3) & 7) | (((gidx >> 8) & 3) << 3);
        float4 v[4];
        #pragma unroll
        for (int j = 0; j < 4; ++j)
          v[j] = *(const float4*)(xb + (size_t)(n4g*4 + j)*DD + dcq*4);
        unsigned short hh[4][4], ll[4][4];
        #pragma unroll
        for (int j = 0; j < 4; ++j)
          #pragma unroll
          for (int i = 0; i < 4; ++i){
            float f = (&v[j].x)[i];
            unsigned short h = f2bf(f);
            hh[j][i] = h;
            ll[j][i] = f2bf(f - bf2f(h));
          }
        #pragma unroll
        for (int i = 0; i < 4; ++i){
          int d = dcq*4 + i;
          int off = d*128 + ((((n4g >> 1) ^ (d & 7)) << 3) + (n4g & 1)*4);
          *(ushort4*)(xh + off) = make_ushort4(hh[0][i], hh[1][i], hh[2][i], hh[3][i]);
          *(ushort4*)(xl + off) = make_ushort4(ll[0][i], ll[1][i], ll[2][i], ll[3][i]);
        }
        // x hi-bf16 in the out-GEMM's swizzled [n][d] LDS image
        #pragma unroll
        for (int j = 0; j < 4; ++j){
          int n = n4g*4 + j;
          int off = n*128 + ((((dcq >> 1) ^ (n & 7)) << 3) + (dcq & 1)*4);
          *(ushort4*)(xbo + off) = make_ushort4(hh[j][0], hh[j][1], hh[j][2], hh[j][3]);
        }
      }
      __syncthreads();
      for (int kc = 0; kc < 4; ++kc){
        bf16x8 ah[2], al[2], bh[4], bl[4];
        #pragma unroll
        for (int r = 0; r < 2; ++r){
          ah[r] = ldfrag_sw(xh, wr + r*16, kc, lane);
          al[r] = ldfrag_sw(xl, wr + r*16, kc, lane);
        }
        #pragma unroll
        for (int c = 0; c < 4; ++c){
          bh[c] = ldfrag_sw(xh, wc + c*16, kc, lane);
          bl[c] = ldfrag_sw(xl, wc + c*16, kc, lane);
        }
        #pragma unroll
        for (int r = 0; r < 2; ++r)
          #pragma unroll
          for (int c = 0; c < 4; ++c){
            acc[r][c] = MFMA_BF16(ah[r], bh[c], acc[r][c], 0, 0, 0);
            acc[r][c] = MFMA_BF16(ah[r], bl[c], acc[r][c], 0, 0, 0);
            acc[r][c] = MFMA_BF16(al[r], bh[c], acc[r][c], 0, 0, 0);
          }
      }
    }
    __syncthreads();
    float* Sf = (float*)sm;    // fp32 [128][128] = 64 KB
    #pragma unroll
    for (int r = 0; r < 2; ++r)
      #pragma unroll
      for (int c = 0; c < 4; ++c)
        #pragma unroll
        for (int reg = 0; reg < 4; ++reg)
          Sf[(wr + r*16 + quad*4 + reg)*128 + wc + c*16 + (lane & 15)] = acc[r][c][reg];
    __syncthreads();
    unsigned short* gp = Gp_bf + ((size_t)(chunk*32 + b) << 14);
    for (int i = t; i < 2048; i += 512){
      int r = i >> 4, c8 = (i & 15) * 8;
      const float* s = Sf + r*128 + c8;
      uint4 o;
      o.x = pack2(s[0], s[1]); o.y = pack2(s[2], s[3]);
      o.z = pack2(s[4], s[5]); o.w = pack2(s[6], s[7]);
      *(uint4*)(gp + r*128 + c8) = o;
    }
  } else {
    // ---- kp: P[h] quarter + Wv[h] quarter cvt; 32 blocks (h, rt) ----
    float* Aq = (float*)sm;          // [64][36]
    float* Bk = Aq + 64*36;          // [64][132]
    const int kpid = bid - 256;
    const int h = kpid >> 2, rt = kpid & 3;
    const int i0 = rt * 32;
    const int tr = t >> 6, tc = t & 63;
    // Wv cvt -> bf16 pre-swizzled [e][d] frag image (rows rt*32..+32)
    {
      const float* wvh = Wv + (size_t)h*DD*DD;
      unsigned short* wvo = Wv_bf + (size_t)h*16384;
      for (int i = t; i < 1024; i += 512){
        int el = i >> 5, dc = (i & 31)*4;
        int e = i0 + el;
        float4 v = *(const float4*)(wvh + (size_t)e*DD + dc);
        int off = e*128 + ((((dc >> 3) ^ (e & 7)) << 3) + (dc & 4));
        *(ushort4*)(wvo + off) = make_ushort4(f2bf(v.x), f2bf(v.y), f2bf(v.z), f2bf(v.w));
      }
    }
    const float* wq = Wq + h*KK*DD;
    const float* wk = Wk + h*KK*DD;
    for (int i = t; i < 512; i += 512){
      int k = i >> 3, c4 = (i & 7) << 2;
      *(float4*)(&Aq[k*36 + c4]) = *(const float4*)(wq + k*DD + i0 + c4);
    }
    for (int i = t; i < 2048; i += 512){
      int k = i >> 5, c4 = (i & 31) << 2;
      *(float4*)(&Bk[k*132 + c4]) = *(const float4*)(wk + k*DD + c4);
    }
    __syncthreads();
    float acc[4][2] = {};
    for (int k = 0; k < 64; k += 2){
      float a0[4], a1[4], b0[2], b1[2];
      *(float4*)a0 = *(float4*)(&Aq[k*36 + tr*4]);
      *(float4*)a1 = *(float4*)(&Aq[(k+1)*36 + tr*4]);
      b0[0] = Bk[k*132 + tc*2];     b0[1] = Bk[k*132 + tc*2 + 1];
      b1[0] = Bk[(k+1)*132 + tc*2]; b1[1] = Bk[(k+1)*132 + tc*2 + 1];
      #pragma unroll
      for (int i = 0; i < 4; ++i)
        #pragma unroll
        for (int j = 0; j < 2; ++j){
          acc[i][j] += a0[i]*b0[j];
          acc[i][j] += a1[i]*b1[j];
        }
    }
    unsigned short* Ph = Pbf + h*DD*DD;
    #pragma unroll
    for (int i = 0; i < 4; ++i){
      int r = i0 + tr*4 + i, c = tc*2;
      int off = r*128 + ((((c >> 3) ^ (r & 7)) << 3) + (c & 7));
      *(ushort2*)(&Ph[off]) = make_ushort2(f2bf(acc[i][0]), f2bf(acc[i][1]));
    }
  }
}

// ---------------- K2: kall — per (b,ntg): reduce Gp->G; M = sum_h P_h (G Wv_h^T); out tiles ----------------
// LDS 96 KB: Gs(32K: G / x-tile / Sf-lo) | Ps(32K: P_h / Sf-hi) | Bs(32K: Wv_h -> T^T -> M^T)
__global__ __launch_bounds__(512, 2) void kall(const unsigned short* __restrict__ Gp_bf,
                                               const unsigned short* __restrict__ Wv_bf,
                                               const unsigned short* __restrict__ Pbf,
                                               const unsigned short* __restrict__ x_bf,
                                               float* __restrict__ out){
  __shared__ __align__(16) unsigned short sm[49152];   // 96 KB
  unsigned short* Gs = sm;
  unsigned short* Ps = sm + 16384;
  unsigned short* Bs = sm + 32768;
  const int bid = blockIdx.x;
  const int b = bid & 31, ntg = bid >> 5;      // ntg in [0,8): 2 n-tiles each
  const int t = threadIdx.x;
  const int w = t >> 6, lane = t & 63, quad = lane >> 4;

  // issue h=0 staging loads (reg prestage, T14)
  uint4 wreg[4], preg[4];
  #pragma unroll
  for (int r = 0; r < 4; ++r){
    wreg[r] = *(const uint4*)(Wv_bf + (size_t)(r*512 + t)*8);
    preg[r] = *(const uint4*)(Pbf   + (size_t)(r*512 + t)*8);
  }
  // G-reduce (8 bf16 partials, fp32) -> Gs swizzled  [bit-identical to R0 km2]
  for (int i = t; i < 2048; i += 512){
    int r = i >> 4, c8 = (i & 15) * 8;
    float s[8] = {};
    #pragma unroll
    for (int p = 0; p < 8; ++p){
      uint4 u = *(const uint4*)(Gp_bf + (((size_t)(p*32 + b)) << 14) + r*128 + c8);
      const unsigned short* pu = (const unsigned short*)&u;
      #pragma unroll
      for (int j = 0; j < 8; ++j) s[j] += bf2f(pu[j]);
    }
    uint4 o;
    o.x = pack2(s[0], s[1]); o.y = pack2(s[2], s[3]);
    o.z = pack2(s[4], s[5]); o.w = pack2(s[6], s[7]);
    *(uint4*)(Gs + r*128 + ((((c8 >> 3) ^ (r & 7))) << 3)) = o;
  }
  // write h=0 staging to LDS; issue h=1 loads
  #pragma unroll
  for (int r = 0; r < 4; ++r){
    *(uint4*)(Bs + (r*512 + t)*8) = wreg[r];
    *(uint4*)(Ps + (r*512 + t)*8) = preg[r];
  }
  #pragma unroll
  for (int r = 0; r < 4; ++r){
    wreg[r] = *(const uint4*)(Wv_bf + 16384 + (size_t)(r*512 + t)*8);
    preg[r] = *(const uint4*)(Pbf   + 16384 + (size_t)(r*512 + t)*8);
  }
  __syncthreads();

  // h-loop: macc += P_h * (G * Wv_h^T), fp32 accumulation across heads
  f32x4 macc[8] = {};
  for (int h = 0; h < 8; ++h){
    // GEMM1: T = G * Wv_h^T; wave w owns d-tile w, all 8 e-tiles
    f32x4 acc1[8] = {};
    for (int kc = 0; kc < 4; ++kc){
      bf16x8 a = ldfrag_sw(Gs, w*16, kc, lane);
      bf16x8 bb[8];
      #pragma unroll
      for (int c = 0; c < 8; ++c) bb[c] = ldfrag_sw(Bs, c*16, kc, lane);
      #pragma unroll
      for (int c = 0; c < 8; ++c) acc1[c] = MFMA_BF16(a, bb[c], acc1[c], 0, 0, 0);
    }
    __syncthreads();
    // T^T -> Bs (swizzled [e][d])
    #pragma unroll
    for (int c = 0; c < 8; ++c){
      int e = c*16 + (lane & 15);
      int d0 = w*16 + quad*4;
      int off = e*128 + ((((d0 >> 3) ^ (e & 7)) << 3) + (d0 & 7));
      *(ushort4*)(Bs + off) = make_ushort4(f2bf(acc1[c][0]), f2bf(acc1[c][1]),
                                           f2bf(acc1[c][2]), f2bf(acc1[c][3]));
    }
    __syncthreads();
    // GEMM2: macc += P_h * T
    for (int kc = 0; kc < 4; ++kc){
      bf16x8 a = ldfrag_sw(Ps, w*16, kc, lane);
      bf16x8 bb[8];
      #pragma unroll
      for (int c = 0; c < 8; ++c) bb[c] = ldfrag_sw(Bs, c*16, kc, lane);
      #pragma unroll
      for (int c = 0; c < 8; ++c) macc[c] = MFMA_BF16(a, bb[c], macc[c], 0, 0, 0);
    }
    __syncthreads();
    if (h < 7){
      #pragma unroll
      for (int r = 0; r < 4; ++r){
        *(uint4*)(Bs + (r*512 + t)*8) = wreg[r];
        *(uint4*)(Ps + (r*512 + t)*8) = preg[r];
      }
      if (h < 6){
        #pragma unroll
        for (int r = 0; r < 4; ++r){
          wreg[r] = *(const uint4*)(Wv_bf + (size_t)(h+2)*16384 + (size_t)(r*512 + t)*8);
          preg[r] = *(const uint4*)(Pbf   + (size_t)(h+2)*16384 + (size_t)(r*512 + t)*8);
        }
      }
      __syncthreads();
    }
  }
  // M^T -> Bs (swizzled [e][d] frag image, single fp32->bf16 rounding)
  #pragma unroll
  for (int c = 0; c < 8; ++c){
    int e = c*16 + (lane & 15);
    int d0 = w*16 + quad*4;
    int off = e*128 + ((((d0 >> 3) ^ (e & 7)) << 3) + (d0 & 7));
    *(ushort4*)(Bs + off) = make_ushort4(f2bf(macc[c][0]), f2bf(macc[c][1]),
                                         f2bf(macc[c][2]), f2bf(macc[c][3]));
  }
  __syncthreads();

  // out phase: 2 n-tiles (ko2 pattern)
  const int wr = (w >> 1)*32, wc = (w & 1)*64;
  for (int i2 = 0; i2 < 2; ++i2){
    int nt = ntg*2 + i2;
    const unsigned short* xbf = x_bf + (((size_t)(b*16 + nt)) << 14);
    for (int i = t; i < 2048; i += 512)
      *(uint4*)(Gs + i*8) = *(const uint4*)(xbf + i*8);
    __syncthreads();
    f32x4 acc[2][4] = {};
    for (int kc = 0; kc < 4; ++kc){
      bf16x8 a[2], bb[4];
      #pragma unroll
      for (int r = 0; r < 2; ++r) a[r] = ldfrag_sw(Gs, wr + r*16, kc, lane);
      #pragma unroll
      for (int c = 0; c < 4; ++c) bb[c] = ldfrag_sw(Bs, wc + c*16, kc, lane);
      #pragma unroll
      for (int r = 0; r < 2; ++r)
        #pragma unroll
        for (int c = 0; c < 4; ++c)
          acc[r][c] = MFMA_BF16(a[r], bb[c], acc[r][c], 0, 0, 0);
    }
    __syncthreads();
    float* Sf = (float*)sm;   // [128][128] fp32 over Gs+Ps (64 KB); Bs untouched
    #pragma unroll
    for (int r = 0; r < 2; ++r)
      #pragma unroll
      for (int c = 0; c < 4; ++c)
        #pragma unroll
        for (int reg = 0; reg < 4; ++reg)
          Sf[(wr + r*16 + quad*4 + reg)*128 + wc + c*16 + (lane & 15)] = acc[r][c][reg];
    __syncthreads();
    float* ob = out + ((size_t)b*NN + (size_t)nt*128)*DD;
    for (int i = t; i < 4096; i += 512){
      int n = i >> 5, c4 = (i & 31) * 4;
      *(float4*)(ob + (size_t)n*DD + c4) = *(const float4*)(Sf + n*128 + c4);
    }
    if (i2 == 0) __syncthreads();   // protect Sf/Gs before next tile's copy
  }
}

extern "C" void kernel_launch(void* const* d_in, const int* in_sizes, int n_in,
                              void* d_out, int out_size, void* d_ws, size_t ws_size,
                              hipStream_t stream){
  const float* x  = (const float*)d_in[0];
  const float* Wk = (const float*)d_in[1];
  const float* Wq = (const float*)d_in[2];
  const float* Wv = (const float*)d_in[3];
  float* out = (float*)d_out;
  unsigned short* wsu = (unsigned short*)d_ws;
  unsigned short* Gp_bf = wsu;               // 4194304
  unsigned short* Pbf   = wsu + 4194304;     // 131072
  unsigned short* Wv_bf = wsu + 4325376;     // 131072
  unsigned short* x_bf  = wsu + 4456448;     // 8388608

  kgkp<<<288, 512, 0, stream>>>(x, Wq, Wk, Wv, Gp_bf, Pbf, Wv_bf, x_bf);
  kall<<<256, 512, 0, stream>>>(Gp_bf, Wv_bf, Pbf, x_bf, out);
}

// Round 6
// 129.523 us; speedup vs baseline: 1.1842x; 1.1842x over previous
//
#include <hip/hip_runtime.h>

#define BB 32
#define NN 2048
#define DD 128
#define HH 8
#define KK 64

typedef __attribute__((ext_vector_type(8))) short bf16x8;
typedef __attribute__((ext_vector_type(4))) float f32x4;
#define MFMA_BF16 __builtin_amdgcn_mfma_f32_16x16x32_bf16

// ws layout (ushort units):
//   Gp_bf : [8][32][128][128]  @ 0        (4194304)
//   Mp_bf : [32][8][128][128]  @ 4194304  (4194304)   (natural [d][e])
//   Pbf   : [8][128][128]      @ 8388608  (131072)    (natural)
//   Mtbf  : [32][128][128]     @ 8519680  (524288)    (transposed [e][d], natural)

__device__ __forceinline__ float bf2f(unsigned short h){ return __uint_as_float(((unsigned)h) << 16); }
__device__ __forceinline__ unsigned short f2bf(float f){
  unsigned u = __float_as_uint(f);
  u += 0x7fffu + ((u >> 16) & 1u);   // RTNE
  return (unsigned short)(u >> 16);
}
__device__ __forceinline__ unsigned pack2(float a, float b){
  return (unsigned)f2bf(a) | ((unsigned)f2bf(b) << 16);
}

// swizzled frag load: phys_ushort(r,c) = r*128 + ((c>>3)^(r&7))*8 + (c&7)
__device__ __forceinline__ bf16x8 ldfrag_sw(const unsigned short* base, int row16, int kc, int lane){
  int d = row16 + (lane & 15);
  int q = lane >> 4;
  int ch = ((kc << 2) + q) ^ (d & 7);
  return *(const bf16x8*)(base + d*128 + ch*8);
}

// Sf bank-conflict swizzle: 4-way -> 2-way (free). col' = col ^ (((row>>2)&1)<<4)
__device__ __forceinline__ int sfswz(int row, int col){ return col ^ (((row >> 2) & 1) << 4); }

// ---------------- K1: kg (blocks 0..255, 256-row chunks) + kp (256..287) ----------------
__global__ __launch_bounds__(512, 2) void kgkp(const float* __restrict__ x,
                                               const float* __restrict__ Wq,
                                               const float* __restrict__ Wk,
                                               unsigned short* __restrict__ Gp_bf,
                                               unsigned short* __restrict__ Pbf){
  __shared__ __align__(16) unsigned short sm[32768];   // 64 KB
  const int t = threadIdx.x;
  const int bid = blockIdx.x;
  const int w = t >> 6, lane = t & 63, quad = lane >> 4;
  if (bid < 256){
    unsigned short* xh = sm;            // hi bf16, swizzled [d][n]
    unsigned short* xl = sm + 16384;    // lo
    const int b = bid & 31, chunk = bid >> 5;          // chunk in [0,8), 256 rows
    const int wr = (w >> 1)*32, wc = (w & 1)*64;
    f32x4 acc[2][4] = {};
    int n4g[2], dcq[2];
    #pragma unroll
    for (int it = 0; it < 2; ++it){
      int gidx = it*512 + t;
      n4g[it] = (gidx & 7) | (((gidx >> 6) & 3) << 3);
      dcq[it] = ((gidx >> 3) & 7) | (((gidx >> 8) & 3) << 3);
    }
    const float* xb0 = x + ((size_t)b*NN + (size_t)(chunk*256))*DD;
    const float* xb1 = xb0 + (size_t)128*DD;
    float4 v[2][4];

    auto cvt_store = [&](){
      #pragma unroll
      for (int it = 0; it < 2; ++it){
        unsigned short hh[4][4], ll[4][4];
        #pragma unroll
        for (int j = 0; j < 4; ++j)
          #pragma unroll
          for (int i = 0; i < 4; ++i){
            float f = (&v[it][j].x)[i];
            unsigned short h = f2bf(f);
            hh[j][i] = h;
            ll[j][i] = f2bf(f - bf2f(h));
          }
        #pragma unroll
        for (int i = 0; i < 4; ++i){
          int d = dcq[it]*4 + i;
          int off = d*128 + ((((n4g[it] >> 1) ^ (d & 7)) << 3) + (n4g[it] & 1)*4);
          *(ushort4*)(xh + off) = make_ushort4(hh[0][i], hh[1][i], hh[2][i], hh[3][i]);
          *(ushort4*)(xl + off) = make_ushort4(ll[0][i], ll[1][i], ll[2][i], ll[3][i]);
        }
      }
    };
    auto mfma_pass = [&](){
      for (int kc = 0; kc < 4; ++kc){
        bf16x8 ah[2], al[2], bh[4], bl[4];
        #pragma unroll
        for (int r = 0; r < 2; ++r){
          ah[r] = ldfrag_sw(xh, wr + r*16, kc, lane);
          al[r] = ldfrag_sw(xl, wr + r*16, kc, lane);
        }
        #pragma unroll
        for (int c = 0; c < 4; ++c){
          bh[c] = ldfrag_sw(xh, wc + c*16, kc, lane);
          bl[c] = ldfrag_sw(xl, wc + c*16, kc, lane);
        }
        #pragma unroll
        for (int r = 0; r < 2; ++r)
          #pragma unroll
          for (int c = 0; c < 4; ++c){
            acc[r][c] = MFMA_BF16(ah[r], bh[c], acc[r][c], 0, 0, 0);
            acc[r][c] = MFMA_BF16(ah[r], bl[c], acc[r][c], 0, 0, 0);
            acc[r][c] = MFMA_BF16(al[r], bh[c], acc[r][c], 0, 0, 0);
          }
      }
    };

    // sub0 loads -> cvt+LDS
    #pragma unroll
    for (int it = 0; it < 2; ++it)
      #pragma unroll
      for (int j = 0; j < 4; ++j)
        v[it][j] = *(const float4*)(xb0 + (size_t)(n4g[it]*4 + j)*DD + dcq[it]*4);
    cvt_store();
    // T14: issue sub1 loads BEFORE sub0 MFMA (latency hides under MFMA phase)
    #pragma unroll
    for (int it = 0; it < 2; ++it)
      #pragma unroll
      for (int j = 0; j < 4; ++j)
        v[it][j] = *(const float4*)(xb1 + (size_t)(n4g[it]*4 + j)*DD + dcq[it]*4);
    __syncthreads();
    mfma_pass();            // sub0
    __syncthreads();
    cvt_store();            // sub1 (vmcnt wait lands here)
    __syncthreads();
    mfma_pass();            // sub1
    __syncthreads();

    float* Sf = (float*)sm;    // fp32 [128][128] = 64 KB, col-swizzled
    #pragma unroll
    for (int r = 0; r < 2; ++r)
      #pragma unroll
      for (int c = 0; c < 4; ++c)
        #pragma unroll
        for (int reg = 0; reg < 4; ++reg){
          int row = wr + r*16 + quad*4 + reg;
          Sf[row*128 + sfswz(row, wc + c*16 + (lane & 15))] = acc[r][c][reg];
        }
    __syncthreads();
    unsigned short* gp = Gp_bf + ((size_t)(chunk*32 + b) << 14);
    for (int i = t; i < 2048; i += 512){
      int r = i >> 4, c8 = (i & 15) * 8;
      const float* s = Sf + r*128 + sfswz(r, c8);
      uint4 o;
      o.x = pack2(s[0], s[1]); o.y = pack2(s[2], s[3]);
      o.z = pack2(s[4], s[5]); o.w = pack2(s[6], s[7]);
      *(uint4*)(gp + r*128 + c8) = o;
    }
  } else {
    // ---- kp: P[h] = Wq^T Wk, 32 blocks, 512 threads ----
    float* Aq = (float*)sm;          // [64][36]
    float* Bk = Aq + 64*36;          // [64][132]
    const int kpid = bid - 256;
    const int h = kpid >> 2, rt = kpid & 3;
    const int i0 = rt * 32;
    const int tr = t >> 6, tc = t & 63;
    const float* wq = Wq + h*KK*DD;
    const float* wk = Wk + h*KK*DD;
    for (int i = t; i < 512; i += 512){
      int k = i >> 3, c4 = (i & 7) << 2;
      *(float4*)(&Aq[k*36 + c4]) = *(const float4*)(wq + k*DD + i0 + c4);
    }
    for (int i = t; i < 2048; i += 512){
      int k = i >> 5, c4 = (i & 31) << 2;
      *(float4*)(&Bk[k*132 + c4]) = *(const float4*)(wk + k*DD + c4);
    }
    __syncthreads();
    float acc[4][2] = {};
    for (int k = 0; k < 64; k += 2){
      float a0[4], a1[4], b0[2], b1[2];
      *(float4*)a0 = *(float4*)(&Aq[k*36 + tr*4]);
      *(float4*)a1 = *(float4*)(&Aq[(k+1)*36 + tr*4]);
      b0[0] = Bk[k*132 + tc*2];     b0[1] = Bk[k*132 + tc*2 + 1];
      b1[0] = Bk[(k+1)*132 + tc*2]; b1[1] = Bk[(k+1)*132 + tc*2 + 1];
      #pragma unroll
      for (int i = 0; i < 4; ++i)
        #pragma unroll
        for (int j = 0; j < 2; ++j){
          acc[i][j] += a0[i]*b0[j];
          acc[i][j] += a1[i]*b1[j];
        }
    }
    unsigned short* Ph = Pbf + h*DD*DD;
    #pragma unroll
    for (int i = 0; i < 4; ++i)
      *(ushort2*)(&Ph[(i0 + tr*4 + i)*DD + tc*2]) =
          make_ushort2(f2bf(acc[i][0]), f2bf(acc[i][1]));
  }
}

// ---------------- K2: per (b,h): reduce Gp->G; T = G@Wv^T (full); M = P@T (full) ----------------
__global__ __launch_bounds__(512, 2) void km2(const unsigned short* __restrict__ Gp_bf,
                                              const float* __restrict__ Wv,
                                              const unsigned short* __restrict__ Pbf,
                                              unsigned short* __restrict__ Mp_bf){
  __shared__ __align__(16) unsigned short sm[32768];   // As | Bs, 64 KB
  unsigned short* As = sm;           // G then P, swizzled [d][k]
  unsigned short* Bs = sm + 16384;   // Wv then T^T, swizzled [e][k]
  const int bid = blockIdx.x;
  const int b = bid & 31, h = bid >> 5;
  const int t = threadIdx.x;
  const int w = t >> 6, lane = t & 63, quad = lane >> 4;
  // T14: prefetch P (consumed only after GEMM1) into regs at kernel start
  const unsigned short* Ph = Pbf + (size_t)h*DD*DD;
  uint4 preg[4];
  #pragma unroll
  for (int ri = 0; ri < 4; ++ri)
    preg[ri] = *(const uint4*)(Ph + (size_t)(ri*512 + t)*8);
  // reduce 8 bf16 G-partials (fp32) -> As swizzled
  for (int i = t; i < 2048; i += 512){
    int r = i >> 4, c8 = (i & 15) * 8;
    float s[8] = {};
    #pragma unroll
    for (int p = 0; p < 8; ++p){
      uint4 u = *(const uint4*)(Gp_bf + (((size_t)(p*32 + b)) << 14) + r*128 + c8);
      const unsigned short* pu = (const unsigned short*)&u;
      #pragma unroll
      for (int j = 0; j < 8; ++j) s[j] += bf2f(pu[j]);
    }
    uint4 o;
    o.x = pack2(s[0], s[1]); o.y = pack2(s[2], s[3]);
    o.z = pack2(s[4], s[5]); o.w = pack2(s[6], s[7]);
    *(uint4*)(As + r*128 + ((((c8 >> 3) ^ (r & 7))) << 3)) = o;
  }
  // stage Wv[h] full (cvt bf16, swizzled [e][d'])
  const float* Wvh = Wv + (size_t)h*DD*DD;
  for (int i = t; i < 4096; i += 512){
    int e = i >> 5, dc = (i & 31) * 4;
    float4 v = *(const float4*)(Wvh + (size_t)e*DD + dc);
    int off = e*128 + ((((dc >> 3) ^ (e & 7)) << 3) + (dc & 4));
    *(ushort4*)(Bs + off) = make_ushort4(f2bf(v.x), f2bf(v.y), f2bf(v.z), f2bf(v.w));
  }
  __syncthreads();
  // phase 1: T[d][e] = G @ Wv^T; wave w owns d-tile w, all 8 e-tiles
  f32x4 acc1[8] = {};
  for (int kc = 0; kc < 4; ++kc){
    bf16x8 a = ldfrag_sw(As, w*16, kc, lane);
    bf16x8 bb[8];
    #pragma unroll
    for (int c = 0; c < 8; ++c) bb[c] = ldfrag_sw(Bs, c*16, kc, lane);
    #pragma unroll
    for (int c = 0; c < 8; ++c) acc1[c] = MFMA_BF16(a, bb[c], acc1[c], 0, 0, 0);
  }
  __syncthreads();
  // write T^T into Bs (swizzled [e][c]); stage prefetched P into As
  #pragma unroll
  for (int c = 0; c < 8; ++c){
    int e = c*16 + (lane & 15);
    int d0 = w*16 + quad*4;
    int off = e*128 + ((((d0 >> 3) ^ (e & 7)) << 3) + (d0 & 7));
    *(ushort4*)(Bs + off) = make_ushort4(f2bf(acc1[c][0]), f2bf(acc1[c][1]),
                                         f2bf(acc1[c][2]), f2bf(acc1[c][3]));
  }
  #pragma unroll
  for (int ri = 0; ri < 4; ++ri){
    int i = ri*512 + t;
    int r = i >> 4, ch = i & 15;
    *(uint4*)(As + r*128 + ((ch ^ (r & 7)) << 3)) = preg[ri];
  }
  __syncthreads();
  // phase 2: M[d][e] = P @ T
  f32x4 acc2[8] = {};
  for (int kc = 0; kc < 4; ++kc){
    bf16x8 a = ldfrag_sw(As, w*16, kc, lane);
    bf16x8 bb[8];
    #pragma unroll
    for (int c = 0; c < 8; ++c) bb[c] = ldfrag_sw(Bs, c*16, kc, lane);
    #pragma unroll
    for (int c = 0; c < 8; ++c) acc2[c] = MFMA_BF16(a, bb[c], acc2[c], 0, 0, 0);
  }
  __syncthreads();
  // epilogue: repack through fp32 LDS -> coalesced bf16 store (natural [d][e])
  float* Sf = (float*)sm;   // [128][128] fp32 = 64 KB, col-swizzled
  #pragma unroll
  for (int c = 0; c < 8; ++c)
    #pragma unroll
    for (int reg = 0; reg < 4; ++reg){
      int row = w*16 + quad*4 + reg;
      Sf[row*128 + sfswz(row, c*16 + (lane & 15))] = acc2[c][reg];
    }
  __syncthreads();
  unsigned short* Mb = Mp_bf + (((size_t)(b*8 + h)) << 14);
  for (int i = t; i < 2048; i += 512){
    int r = i >> 4, c8 = (i & 15) * 8;
    const float* s = Sf + r*128 + sfswz(r, c8);
    uint4 o;
    o.x = pack2(s[0], s[1]); o.y = pack2(s[2], s[3]);
    o.z = pack2(s[4], s[5]); o.w = pack2(s[6], s[7]);
    *(uint4*)(Mb + r*128 + c8) = o;
  }
}

// ---------------- K3: kmr — reduce Mp over h + transpose -> Mtbf[b][e][d] ----------------
__global__ __launch_bounds__(256) void kmr(const unsigned short* __restrict__ Mp_bf,
                                           unsigned short* __restrict__ Mtbf){
  __shared__ float Sf[16][132];
  const int bid = blockIdx.x;
  const int b = bid >> 3, es = bid & 7;       // e-strip of 16
  const int t = threadIdx.x;
  {
    int d = t >> 1, half = t & 1;             // 256 threads cover 128 d x 2 halves
    float s[8] = {};
    #pragma unroll
    for (int h = 0; h < 8; ++h){
      uint4 u = *(const uint4*)(Mp_bf + (((size_t)(b*8 + h)) << 14) + d*128 + es*16 + half*8);
      const unsigned short* pu = (const unsigned short*)&u;
      #pragma unroll
      for (int j = 0; j < 8; ++j) s[j] += bf2f(pu[j]);
    }
    #pragma unroll
    for (int j = 0; j < 8; ++j) Sf[half*8 + j][d] = s[j];
  }
  __syncthreads();
  unsigned short* Mb = Mtbf + ((size_t)b << 14);
  for (int j = t; j < 2048; j += 256){
    int e = j >> 7, d = j & 127;
    Mb[(es*16 + e)*128 + d] = f2bf(Sf[e][d]);
  }
}

// ---------------- K4: ko — out[b,nt] = x_tile @ M (B staged from Mtbf) ----------------
__global__ __launch_bounds__(512, 4) void ko2(const float* __restrict__ x,
                                              const unsigned short* __restrict__ Mtbf,
                                              float* __restrict__ out){
  __shared__ __align__(16) unsigned short sm[32768];   // xs | Ms; epilogue float [n][128]
  unsigned short* xs = sm;           // x tile bf16, swizzled [n][d]
  unsigned short* Ms = sm + 16384;   // M^T bf16, swizzled [e][d]
  const int bid = blockIdx.x;
  const int b = bid & 31, nt = bid >> 5;
  const int t = threadIdx.x;
  const int w = t >> 6, lane = t & 63, quad = lane >> 4;
  const float* xb = x + ((size_t)b*NN + (size_t)nt*128)*DD;
  const unsigned short* Mtb = Mtbf + ((size_t)b << 14);
  for (int i = t; i < 4096; i += 512){
    int n = i >> 5, dcq = i & 31;
    float4 v = *(const float4*)(xb + (size_t)n*DD + dcq*4);
    int off = n*128 + ((((dcq >> 1) ^ (n & 7)) << 3) + (dcq & 1)*4);
    *(ushort4*)(xs + off) = make_ushort4(f2bf(v.x), f2bf(v.y), f2bf(v.z), f2bf(v.w));
  }
  for (int i = t; i < 2048; i += 512){
    int e = i >> 4, ng = i & 15;
    *(uint4*)(Ms + e*128 + ((ng ^ (e & 7)) << 3)) = *(const uint4*)(Mtb + e*128 + ng*8);
  }
  __syncthreads();
  const int wr = (w >> 1)*32, wc = (w & 1)*64;
  f32x4 acc[2][4] = {};
  for (int kc = 0; kc < 4; ++kc){
    bf16x8 a[2], bb[4];
    #pragma unroll
    for (int r = 0; r < 2; ++r) a[r] = ldfrag_sw(xs, wr + r*16, kc, lane);
    #pragma unroll
    for (int c = 0; c < 4; ++c) bb[c] = ldfrag_sw(Ms, wc + c*16, kc, lane);
    #pragma unroll
    for (int r = 0; r < 2; ++r)
      #pragma unroll
      for (int c = 0; c < 4; ++c)
        acc[r][c] = MFMA_BF16(a[r], bb[c], acc[r][c], 0, 0, 0);
  }
  __syncthreads();
  float* Sf = (float*)sm;   // [n][128] fp32, 64 KB, col-swizzled
  #pragma unroll
  for (int r = 0; r < 2; ++r)
    #pragma unroll
    for (int c = 0; c < 4; ++c)
      #pragma unroll
      for (int reg = 0; reg < 4; ++reg){
        int row = wr + r*16 + quad*4 + reg;
        Sf[row*128 + sfswz(row, wc + c*16 + (lane & 15))] = acc[r][c][reg];
      }
  __syncthreads();
  float* ob = out + ((size_t)b*NN + (size_t)nt*128)*DD;
  for (int i = t; i < 4096; i += 512){
    int n = i >> 5, c4 = (i & 31) * 4;
    *(float4*)(ob + (size_t)n*DD + c4) = *(const float4*)(Sf + n*128 + sfswz(n, c4));
  }
}

extern "C" void kernel_launch(void* const* d_in, const int* in_sizes, int n_in,
                              void* d_out, int out_size, void* d_ws, size_t ws_size,
                              hipStream_t stream){
  const float* x  = (const float*)d_in[0];
  const float* Wk = (const float*)d_in[1];
  const float* Wq = (const float*)d_in[2];
  const float* Wv = (const float*)d_in[3];
  float* out = (float*)d_out;
  unsigned short* wsu = (unsigned short*)d_ws;
  unsigned short* Gp_bf = wsu;               // 4194304
  unsigned short* Mp_bf = wsu + 4194304;     // 4194304
  unsigned short* Pbf   = wsu + 8388608;     // 131072
  unsigned short* Mtbf  = wsu + 8519680;     // 524288

  kgkp<<<288, 512, 0, stream>>>(x, Wq, Wk, Gp_bf, Pbf);
  km2 <<<256, 512, 0, stream>>>(Gp_bf, Wv, Pbf, Mp_bf);
  kmr <<<256, 256, 0, stream>>>(Mp_bf, Mtbf);
  ko2 <<<512, 512, 0, stream>>>(x, Mtbf, out);
}

// Round 7
// 121.122 us; speedup vs baseline: 1.2663x; 1.0694x over previous
//
#include <hip/hip_runtime.h>

#define BB 32
#define NN 2048
#define DD 128
#define HH 8
#define KK 64

typedef __attribute__((ext_vector_type(8))) short bf16x8;
typedef __attribute__((ext_vector_type(4))) float f32x4;
#define MFMA_BF16 __builtin_amdgcn_mfma_f32_16x16x32_bf16

// ws layout (ushort units):
//   Gp_bf : [8][32][128][128]  @ 0        (4194304)  bf16 Gram partials (natural)
//   Mp_t  : [32][8][128][128]  @ 4194304  (4194304)  per-head M, TRANSPOSED [e][d]
//   Pbf   : [8][128][128]      @ 8388608  (131072)   P = Wq^T Wk (natural)

__device__ __forceinline__ float bf2f(unsigned short h){ return __uint_as_float(((unsigned)h) << 16); }
__device__ __forceinline__ unsigned short f2bf(float f){
  unsigned u = __float_as_uint(f);
  u += 0x7fffu + ((u >> 16) & 1u);   // RTNE
  return (unsigned short)(u >> 16);
}
__device__ __forceinline__ unsigned pack2(float a, float b){
  return (unsigned)f2bf(a) | ((unsigned)f2bf(b) << 16);
}

// swizzled frag load: phys_ushort(r,c) = r*128 + ((c>>3)^(r&7))*8 + (c&7)
__device__ __forceinline__ bf16x8 ldfrag_sw(const unsigned short* base, int row16, int kc, int lane){
  int d = row16 + (lane & 15);
  int q = lane >> 4;
  int ch = ((kc << 2) + q) ^ (d & 7);
  return *(const bf16x8*)(base + d*128 + ch*8);
}

// ---------------- K1: kg (blocks 0..255, 256-row chunks) + kp (256..287) ----------------
__global__ __launch_bounds__(512, 4) void kgkp(const float* __restrict__ x,
                                               const float* __restrict__ Wq,
                                               const float* __restrict__ Wk,
                                               unsigned short* __restrict__ Gp_bf,
                                               unsigned short* __restrict__ Pbf){
  __shared__ __align__(16) unsigned short sm[32768];   // 64 KB
  const int t = threadIdx.x;
  const int bid = blockIdx.x;
  const int w = t >> 6, lane = t & 63, quad = lane >> 4;
  if (bid < 256){
    unsigned short* xh = sm;            // hi bf16, swizzled [d][n]
    unsigned short* xl = sm + 16384;    // lo
    const int b = bid & 31, chunk = bid >> 5;          // chunk in [0,8), 256 rows
    const int wr = (w >> 1)*32, wc = (w & 1)*64;
    f32x4 acc[2][4] = {};
    for (int sub = 0; sub < 2; ++sub){
      if (sub) __syncthreads();
      const float* xb = x + ((size_t)b*NN + (size_t)(chunk*256 + sub*128))*DD;
      for (int it = 0; it < 2; ++it){
        int gidx = it*512 + t;
        int n4g = (gidx & 7) | (((gidx >> 6) & 3) << 3);
        int dcq = ((gidx >> 3) & 7) | (((gidx >> 8) & 3) << 3);
        float4 v[4];
        #pragma unroll
        for (int j = 0; j < 4; ++j)
          v[j] = *(const float4*)(xb + (size_t)(n4g*4 + j)*DD + dcq*4);
        #pragma unroll
        for (int i = 0; i < 4; ++i){
          int d = dcq*4 + i;
          float f0 = (&v[0].x)[i], f1 = (&v[1].x)[i], f2 = (&v[2].x)[i], f3 = (&v[3].x)[i];
          unsigned short h0 = f2bf(f0), h1 = f2bf(f1), h2 = f2bf(f2), h3 = f2bf(f3);
          unsigned short l0 = f2bf(f0 - bf2f(h0)), l1 = f2bf(f1 - bf2f(h1));
          unsigned short l2 = f2bf(f2 - bf2f(h2)), l3 = f2bf(f3 - bf2f(h3));
          int off = d*128 + ((((n4g >> 1) ^ (d & 7)) << 3) + (n4g & 1)*4);
          *(ushort4*)(xh + off) = make_ushort4(h0, h1, h2, h3);
          *(ushort4*)(xl + off) = make_ushort4(l0, l1, l2, l3);
        }
      }
      __syncthreads();
      for (int kc = 0; kc < 4; ++kc){
        bf16x8 ah[2], al[2], bh[4], bl[4];
        #pragma unroll
        for (int r = 0; r < 2; ++r){
          ah[r] = ldfrag_sw(xh, wr + r*16, kc, lane);
          al[r] = ldfrag_sw(xl, wr + r*16, kc, lane);
        }
        #pragma unroll
        for (int c = 0; c < 4; ++c){
          bh[c] = ldfrag_sw(xh, wc + c*16, kc, lane);
          bl[c] = ldfrag_sw(xl, wc + c*16, kc, lane);
        }
        #pragma unroll
        for (int r = 0; r < 2; ++r)
          #pragma unroll
          for (int c = 0; c < 4; ++c){
            acc[r][c] = MFMA_BF16(ah[r], bh[c], acc[r][c], 0, 0, 0);
            acc[r][c] = MFMA_BF16(ah[r], bl[c], acc[r][c], 0, 0, 0);
            acc[r][c] = MFMA_BF16(al[r], bh[c], acc[r][c], 0, 0, 0);
          }
      }
    }
    __syncthreads();
    float* Sf = (float*)sm;    // fp32 [128][128] = 64 KB
    #pragma unroll
    for (int r = 0; r < 2; ++r)
      #pragma unroll
      for (int c = 0; c < 4; ++c)
        #pragma unroll
        for (int reg = 0; reg < 4; ++reg)
          Sf[(wr + r*16 + quad*4 + reg)*128 + wc + c*16 + (lane & 15)] = acc[r][c][reg];
    __syncthreads();
    unsigned short* gp = Gp_bf + ((size_t)(chunk*32 + b) << 14);
    for (int i = t; i < 2048; i += 512){
      int r = i >> 4, c8 = (i & 15) * 8;
      const float* s = Sf + r*128 + c8;
      uint4 o;
      o.x = pack2(s[0], s[1]); o.y = pack2(s[2], s[3]);
      o.z = pack2(s[4], s[5]); o.w = pack2(s[6], s[7]);
      *(uint4*)(gp + r*128 + c8) = o;
    }
  } else {
    // ---- kp: P[h] = Wq^T Wk, 32 blocks, 512 threads ----
    float* Aq = (float*)sm;          // [64][36]
    float* Bk = Aq + 64*36;          // [64][132]
    const int kpid = bid - 256;
    const int h = kpid >> 2, rt = kpid & 3;
    const int i0 = rt * 32;
    const int tr = t >> 6, tc = t & 63;
    const float* wq = Wq + h*KK*DD;
    const float* wk = Wk + h*KK*DD;
    for (int i = t; i < 512; i += 512){
      int k = i >> 3, c4 = (i & 7) << 2;
      *(float4*)(&Aq[k*36 + c4]) = *(const float4*)(wq + k*DD + i0 + c4);
    }
    for (int i = t; i < 2048; i += 512){
      int k = i >> 5, c4 = (i & 31) << 2;
      *(float4*)(&Bk[k*132 + c4]) = *(const float4*)(wk + k*DD + c4);
    }
    __syncthreads();
    float acc[4][2] = {};
    for (int k = 0; k < 64; k += 2){
      float a0[4], a1[4], b0[2], b1[2];
      *(float4*)a0 = *(float4*)(&Aq[k*36 + tr*4]);
      *(float4*)a1 = *(float4*)(&Aq[(k+1)*36 + tr*4]);
      b0[0] = Bk[k*132 + tc*2];     b0[1] = Bk[k*132 + tc*2 + 1];
      b1[0] = Bk[(k+1)*132 + tc*2]; b1[1] = Bk[(k+1)*132 + tc*2 + 1];
      #pragma unroll
      for (int i = 0; i < 4; ++i)
        #pragma unroll
        for (int j = 0; j < 2; ++j){
          acc[i][j] += a0[i]*b0[j];
          acc[i][j] += a1[i]*b1[j];
        }
    }
    unsigned short* Ph = Pbf + h*DD*DD;
    #pragma unroll
    for (int i = 0; i < 4; ++i)
      *(ushort2*)(&Ph[(i0 + tr*4 + i)*DD + tc*2]) =
          make_ushort2(f2bf(acc[i][0]), f2bf(acc[i][1]));
  }
}

// ---------------- K2: per (b,h): reduce Gp->G; T = G@Wv^T; M = P@T; write M TRANSPOSED ----------------
__global__ __launch_bounds__(512, 2) void km2(const unsigned short* __restrict__ Gp_bf,
                                              const float* __restrict__ Wv,
                                              const unsigned short* __restrict__ Pbf,
                                              unsigned short* __restrict__ Mp_t){
  __shared__ __align__(16) unsigned short sm[32768];   // As | Bs, 64 KB
  unsigned short* As = sm;           // G then P, swizzled [d][k]
  unsigned short* Bs = sm + 16384;   // Wv then T^T, swizzled [e][k]
  const int bid = blockIdx.x;
  const int b = bid & 31, h = bid >> 5;
  const int t = threadIdx.x;
  const int w = t >> 6, lane = t & 63, quad = lane >> 4;
  // reduce 8 bf16 G-partials (fp32) -> As swizzled
  for (int i = t; i < 2048; i += 512){
    int r = i >> 4, c8 = (i & 15) * 8;
    float s[8] = {};
    #pragma unroll
    for (int p = 0; p < 8; ++p){
      uint4 u = *(const uint4*)(Gp_bf + (((size_t)(p*32 + b)) << 14) + r*128 + c8);
      const unsigned short* pu = (const unsigned short*)&u;
      #pragma unroll
      for (int j = 0; j < 8; ++j) s[j] += bf2f(pu[j]);
    }
    uint4 o;
    o.x = pack2(s[0], s[1]); o.y = pack2(s[2], s[3]);
    o.z = pack2(s[4], s[5]); o.w = pack2(s[6], s[7]);
    *(uint4*)(As + r*128 + ((((c8 >> 3) ^ (r & 7))) << 3)) = o;
  }
  // stage Wv[h] full (cvt bf16, swizzled [e][d'])
  const float* Wvh = Wv + (size_t)h*DD*DD;
  for (int i = t; i < 4096; i += 512){
    int e = i >> 5, dc = (i & 31) * 4;
    float4 v = *(const float4*)(Wvh + (size_t)e*DD + dc);
    int off = e*128 + ((((dc >> 3) ^ (e & 7)) << 3) + (dc & 4));
    *(ushort4*)(Bs + off) = make_ushort4(f2bf(v.x), f2bf(v.y), f2bf(v.z), f2bf(v.w));
  }
  __syncthreads();
  // phase 1: T[d][e] = G @ Wv^T; wave w owns d-tile w, all 8 e-tiles
  f32x4 acc1[8] = {};
  for (int kc = 0; kc < 4; ++kc){
    bf16x8 a = ldfrag_sw(As, w*16, kc, lane);
    bf16x8 bb[8];
    #pragma unroll
    for (int c = 0; c < 8; ++c) bb[c] = ldfrag_sw(Bs, c*16, kc, lane);
    #pragma unroll
    for (int c = 0; c < 8; ++c) acc1[c] = MFMA_BF16(a, bb[c], acc1[c], 0, 0, 0);
  }
  __syncthreads();
  // write T^T into Bs (swizzled [e][c]); stage P into As
  #pragma unroll
  for (int c = 0; c < 8; ++c){
    int e = c*16 + (lane & 15);
    int d0 = w*16 + quad*4;
    int off = e*128 + ((((d0 >> 3) ^ (e & 7)) << 3) + (d0 & 7));
    *(ushort4*)(Bs + off) = make_ushort4(f2bf(acc1[c][0]), f2bf(acc1[c][1]),
                                         f2bf(acc1[c][2]), f2bf(acc1[c][3]));
  }
  const unsigned short* Ph = Pbf + (size_t)h*DD*DD;
  for (int i = t; i < 2048; i += 512){
    int r = i >> 4, ch = i & 15;
    *(uint4*)(As + r*128 + ((ch ^ (r & 7)) << 3)) = *(const uint4*)(Ph + r*128 + ch*8);
  }
  __syncthreads();
  // phase 2: M[d][e] = P @ T
  f32x4 acc2[8] = {};
  for (int kc = 0; kc < 4; ++kc){
    bf16x8 a = ldfrag_sw(As, w*16, kc, lane);
    bf16x8 bb[8];
    #pragma unroll
    for (int c = 0; c < 8; ++c) bb[c] = ldfrag_sw(Bs, c*16, kc, lane);
    #pragma unroll
    for (int c = 0; c < 8; ++c) acc2[c] = MFMA_BF16(a, bb[c], acc2[c], 0, 0, 0);
  }
  __syncthreads();
  // epilogue: TRANSPOSED repack through fp32 LDS -> coalesced bf16 store of M^T [e][d]
  // LDS col swizzled by ((e&7)<<2) to break the all-lanes-same-column bank conflict
  float* Sf = (float*)sm;   // [e][d] 128x128 fp32 = 64 KB
  #pragma unroll
  for (int c = 0; c < 8; ++c){
    int e = c*16 + (lane & 15);
    int xr = (e & 7) << 2;
    #pragma unroll
    for (int reg = 0; reg < 4; ++reg){
      int d = w*16 + quad*4 + reg;
      Sf[e*128 + (d ^ xr)] = acc2[c][reg];
    }
  }
  __syncthreads();
  unsigned short* Mb = Mp_t + (((size_t)(b*8 + h)) << 14);
  for (int i = t; i < 2048; i += 512){
    int e = i >> 4, c8 = (i & 15) * 8;
    int xr = (e & 7) << 2;
    float4 lo = *(const float4*)(Sf + e*128 + (c8 ^ xr));
    float4 hi = *(const float4*)(Sf + e*128 + ((c8 + 4) ^ xr));
    uint4 o;
    o.x = pack2(lo.x, lo.y); o.y = pack2(lo.z, lo.w);
    o.z = pack2(hi.x, hi.y); o.w = pack2(hi.z, hi.w);
    *(uint4*)(Mb + e*128 + c8) = o;
  }
}

// ---------------- K3: ko — out[b,nt] = x_tile @ M; Ms staged by inline h-reduce of Mp_t ----------------
__global__ __launch_bounds__(512, 4) void ko2(const float* __restrict__ x,
                                              const unsigned short* __restrict__ Mp_t,
                                              float* __restrict__ out){
  __shared__ __align__(16) unsigned short sm[32768];   // xs | Ms; epilogue float [n][128]
  unsigned short* xs = sm;           // x tile bf16, swizzled [n][d]
  unsigned short* Ms = sm + 16384;   // M^T bf16, swizzled [e][d]
  const int bid = blockIdx.x;
  const int b = bid & 31, nt = bid >> 5;
  const int t = threadIdx.x;
  const int w = t >> 6, lane = t & 63, quad = lane >> 4;
  const float* xb = x + ((size_t)b*NN + (size_t)nt*128)*DD;
  for (int i = t; i < 4096; i += 512){
    int n = i >> 5, dcq = i & 31;
    float4 v = *(const float4*)(xb + (size_t)n*DD + dcq*4);
    int off = n*128 + ((((dcq >> 1) ^ (n & 7)) << 3) + (dcq & 1)*4);
    *(ushort4*)(xs + off) = make_ushort4(f2bf(v.x), f2bf(v.y), f2bf(v.z), f2bf(v.w));
  }
  // stage Ms: sum 8 per-head M^T (bf16 -> fp32, h ascending == old kmr order) -> bf16 swizzled
  const unsigned short* Mpb = Mp_t + (((size_t)b * 8) << 14);
  for (int i = t; i < 2048; i += 512){
    int e = i >> 4, dch = i & 15;
    float s[8] = {};
    #pragma unroll
    for (int hh = 0; hh < 8; ++hh){
      uint4 u = *(const uint4*)(Mpb + ((size_t)hh << 14) + e*128 + dch*8);
      const unsigned short* pu = (const unsigned short*)&u;
      #pragma unroll
      for (int j = 0; j < 8; ++j) s[j] += bf2f(pu[j]);
    }
    uint4 o;
    o.x = pack2(s[0], s[1]); o.y = pack2(s[2], s[3]);
    o.z = pack2(s[4], s[5]); o.w = pack2(s[6], s[7]);
    *(uint4*)(Ms + e*128 + ((dch ^ (e & 7)) << 3)) = o;
  }
  __syncthreads();
  const int wr = (w >> 1)*32, wc = (w & 1)*64;
  f32x4 acc[2][4] = {};
  for (int kc = 0; kc < 4; ++kc){
    bf16x8 a[2], bb[4];
    #pragma unroll
    for (int r = 0; r < 2; ++r) a[r] = ldfrag_sw(xs, wr + r*16, kc, lane);
    #pragma unroll
    for (int c = 0; c < 4; ++c) bb[c] = ldfrag_sw(Ms, wc + c*16, kc, lane);
    #pragma unroll
    for (int r = 0; r < 2; ++r)
      #pragma unroll
      for (int c = 0; c < 4; ++c)
        acc[r][c] = MFMA_BF16(a[r], bb[c], acc[r][c], 0, 0, 0);
  }
  __syncthreads();
  float* Sf = (float*)sm;   // [n][128] fp32, 64 KB
  #pragma unroll
  for (int r = 0; r < 2; ++r)
    #pragma unroll
    for (int c = 0; c < 4; ++c)
      #pragma unroll
      for (int reg = 0; reg < 4; ++reg)
        Sf[(wr + r*16 + quad*4 + reg)*128 + wc + c*16 + (lane & 15)] = acc[r][c][reg];
  __syncthreads();
  float* ob = out + ((size_t)b*NN + (size_t)nt*128)*DD;
  for (int i = t; i < 4096; i += 512){
    int n = i >> 5, c4 = (i & 31) * 4;
    *(float4*)(ob + (size_t)n*DD + c4) = *(const float4*)(Sf + n*128 + c4);
  }
}

extern "C" void kernel_launch(void* const* d_in, const int* in_sizes, int n_in,
                              void* d_out, int out_size, void* d_ws, size_t ws_size,
                              hipStream_t stream){
  const float* x  = (const float*)d_in[0];
  const float* Wk = (const float*)d_in[1];
  const float* Wq = (const float*)d_in[2];
  const float* Wv = (const float*)d_in[3];
  float* out = (float*)d_out;
  unsigned short* wsu = (unsigned short*)d_ws;
  unsigned short* Gp_bf = wsu;               // 4194304
  unsigned short* Mp_t  = wsu + 4194304;     // 4194304
  unsigned short* Pbf   = wsu + 8388608;     // 131072

  kgkp<<<288, 512, 0, stream>>>(x, Wq, Wk, Gp_bf, Pbf);
  km2 <<<256, 512, 0, stream>>>(Gp_bf, Wv, Pbf, Mp_t);
  ko2 <<<512, 512, 0, stream>>>(x, Mp_t, out);
}